// Round 9
// baseline (294.326 us; speedup 1.0000x reference)
//
#include <hip/hip_runtime.h>
#include <stdint.h>

typedef _Float16 h8v __attribute__((ext_vector_type(8)));
typedef float f4v __attribute__((ext_vector_type(4)));

#define MFMA(a,b,c) __builtin_amdgcn_mfma_f32_16x16x32_f16((a),(b),(c),0,0,0)
#define NSPLIT 2

__device__ __forceinline__ _Float16 f2h(float f) { return (_Float16)f; }

// swizzled byte offset for conv B-tile: row pitch 64B, 4 chunks of 16B, XOR on (row>>1)&3
__device__ __forceinline__ int swb(int row, int chunk) {
  return row * 64 + (((chunk) ^ ((row >> 1) & 3)) << 4);
}

// ---------------- K1: PE add + transpose:  xpe_t[b][t][c] = f16(x[b][c][t] + pe(t,c))
__global__ __launch_bounds__(256) void k_pe_t(const float* __restrict__ x, _Float16* __restrict__ xpe) {
  __shared__ float tile[32][33];
  int b = blockIdx.z;
  int t0 = blockIdx.x * 32, c0 = blockIdx.y * 32;
  int tid = threadIdx.x;
  int col = tid & 31, rowq = tid >> 5;
#pragma unroll
  for (int i = 0; i < 4; ++i) {
    int c = c0 + rowq + i * 8;
    int t = t0 + col;
    int j2 = c & ~1;
    float dv = expf(-0.01798894603885192f * (float)j2);  // ln(1e4)/512
    float ang = (float)t * dv;
    float pe = (c & 1) ? cosf(ang) : sinf(ang);
    tile[rowq + i * 8][col] = x[((size_t)b * 512 + c) * 2048 + t] + pe;
  }
  __syncthreads();
#pragma unroll
  for (int i = 0; i < 4; ++i) {
    int t = t0 + rowq + i * 8;
    int c = c0 + col;
    xpe[((size_t)b * 2048 + t) * 512 + c] = f2h(tile[col][rowq + i * 8]);
  }
}

// ---------------- K2a: cast projection weights to f16 (four 131072-elem arrays)
__global__ __launch_bounds__(256) void k_cast(const float* __restrict__ a0, const float* __restrict__ a1,
                                              const float* __restrict__ a2, const float* __restrict__ a3,
                                              _Float16* __restrict__ o) {
  int w = blockIdx.y;
  const float* s = (w == 0) ? a0 : (w == 1) ? a1 : (w == 2) ? a2 : a3;
  int i = blockIdx.x * 256 + threadIdx.x;
  o[(size_t)w * 131072 + i] = f2h(s[i]);
}

// ---------------- K2b: cast z_w (512x1536) to f16
__global__ __launch_bounds__(256) void k_castz(const float* __restrict__ zw, _Float16* __restrict__ zh) {
  int i = blockIdx.x * 256 + threadIdx.x;  // grid 3072 -> 786432
  zh[i] = f2h(zw[i]);
}

// ---------------- K2c: transpose-cast temporal conv weights
// src w[m][k*512+c] (512x1536 f32);  dst wt[z][c][m] f16, z = k (w1) or 3+k (w2)
__global__ __launch_bounds__(256) void k_wtrans(const float* __restrict__ w1, const float* __restrict__ w2,
                                                _Float16* __restrict__ wt) {
  int z = blockIdx.z;
  const float* src = (z < 3) ? w1 : w2;
  int k = (z < 3) ? z : z - 3;
  __shared__ _Float16 tile[64][65];
  int m0 = blockIdx.y * 64, c0 = blockIdx.x * 64;
  int tid = threadIdx.x;
  int tc = tid & 63, tm = tid >> 6;  // 4 rows per pass
#pragma unroll
  for (int i = 0; i < 16; ++i) {
    int m = m0 + tm + i * 4;
    tile[tm + i * 4][tc] = f2h(src[(size_t)m * 1536 + (size_t)k * 512 + c0 + tc]);
  }
  __syncthreads();
#pragma unroll
  for (int i = 0; i < 16; ++i) {
    int c = c0 + tm + i * 4;
    wt[((size_t)z * 512 + c) * 512 + m0 + tc] = tile[tc][tm + i * 4];
  }
}

// ---------------- K3: merge conv weights through z (f16 MFMA)
__global__ __launch_bounds__(256) void k_merge(const _Float16* __restrict__ zh,
                                               const _Float16* __restrict__ wt,
                                               const float* __restrict__ zwf,
                                               _Float16* __restrict__ M) {
  int s = blockIdx.z;
  int wid = threadIdx.x >> 6, lane = threadIdx.x & 63;
  int o0 = blockIdx.y * 64 + (wid >> 1) * 32;
  int c0 = blockIdx.x * 64 + (wid & 1) * 32;
  int row16 = lane & 15, kg = lane >> 4, koff = kg * 8;
  f4v acc[2][2];
#pragma unroll
  for (int mi = 0; mi < 2; ++mi)
#pragma unroll
    for (int ni = 0; ni < 2; ++ni) acc[mi][ni] = (f4v){0.f, 0.f, 0.f, 0.f};

  int np = (s == 2) ? 2 : 1;
  for (int p = 0; p < np; ++p) {
    int seg, wi;
    if (s == 0)      { seg = 1024; wi = 3; }
    else if (s == 1) { seg = 512;  wi = 0; }
    else if (s == 3) { seg = 512;  wi = 2; }
    else if (s == 4) { seg = 1024; wi = 5; }
    else             { seg = (p == 0) ? 512 : 1024; wi = (p == 0) ? 1 : 4; }
    const _Float16* A = zh + seg;
    const _Float16* B = wt + (size_t)wi * 512 * 512;
    for (int k0 = 0; k0 < 512; k0 += 32) {
      h8v a[2], bv[2];
#pragma unroll
      for (int i = 0; i < 2; ++i)
        a[i] = *(const h8v*)(A + (size_t)(o0 + i * 16 + row16) * 1536 + k0 + koff);
#pragma unroll
      for (int i = 0; i < 2; ++i)
        bv[i] = *(const h8v*)(B + (size_t)(c0 + i * 16 + row16) * 512 + k0 + koff);
#pragma unroll
      for (int mi = 0; mi < 2; ++mi)
#pragma unroll
        for (int ni = 0; ni < 2; ++ni)
          acc[mi][ni] = MFMA(a[mi], bv[ni], acc[mi][ni]);
    }
  }
  _Float16* dst = M + (size_t)s * 512 * 512;
#pragma unroll
  for (int mi = 0; mi < 2; ++mi)
#pragma unroll
    for (int r = 0; r < 4; ++r) {
      int o = o0 + mi * 16 + kg * 4 + r;
#pragma unroll
      for (int ni = 0; ni < 2; ++ni) {
        int c = c0 + ni * 16 + row16;
        float v = acc[mi][ni][r];
        if (s == 2) v += zwf[(size_t)o * 1536 + c];
        dst[(size_t)o * 512 + c] = f2h(v);
      }
    }
}

// ---------------- shared 64x64-per-wave TN GEMM core (A[M][K], B[N][K], K-contig)
__device__ __forceinline__ void gemm64x64(const _Float16* __restrict__ A, int lda,
                                          const _Float16* __restrict__ B, int ldb,
                                          int K, int lane, f4v acc[4][4]) {
  const int row16 = lane & 15, koff = (lane >> 4) * 8;
  for (int k0 = 0; k0 < K; k0 += 32) {
    h8v a[4], bv[4];
#pragma unroll
    for (int i = 0; i < 4; ++i)
      a[i] = *(const h8v*)(A + (size_t)(i * 16 + row16) * lda + k0 + koff);
#pragma unroll
    for (int i = 0; i < 4; ++i)
      bv[i] = *(const h8v*)(B + (size_t)(i * 16 + row16) * ldb + k0 + koff);
#pragma unroll
    for (int mi = 0; mi < 4; ++mi)
#pragma unroll
      for (int ni = 0; ni < 4; ++ni)
        acc[mi][ni] = MFMA(a[mi], bv[ni], acc[mi][ni]);
  }
}

// ---------------- K4: conv GEMM  x2[o][t] = sum_s M_s[o][:]·xpe[t+s-2][:] + zb
// tile 64(o) x 128(t), 4 waves of 32x64; B-tile 132 rows x 32ch, 64B pitch XOR-swizzled, dbuf.
__global__ __launch_bounds__(256, 4) void k_conv(const _Float16* __restrict__ Mh,
                                                 const _Float16* __restrict__ xpe,
                                                 const float* __restrict__ zb,
                                                 _Float16* __restrict__ x2ct,
                                                 _Float16* __restrict__ x2h) {
  int b = blockIdx.z;
  int o0 = blockIdx.y * 64, t0 = blockIdx.x * 128;
  int tid = threadIdx.x;
  int wid = tid >> 6, lane = tid & 63;
  int wm = (wid >> 1) * 32, wn = (wid & 1) * 64;
  int row16 = lane & 15, kg = lane >> 4, koff = kg * 8;
  __shared__ __align__(16) char bsm[2][132 * 64];
  const _Float16* Xb = xpe + (size_t)b * 2048 * 512;
  const h8v zerov = {0, 0, 0, 0, 0, 0, 0, 0};

  f4v acc[2][4];
#pragma unroll
  for (int mi = 0; mi < 2; ++mi)
#pragma unroll
    for (int ni = 0; ni < 4; ++ni) acc[mi][ni] = (f4v){0.f, 0.f, 0.f, 0.f};

  // staging chunk coordinates (528 chunks of 16B)
  int r0c = tid >> 2,         c0c = tid & 3;
  int r1c = (tid + 256) >> 2, c1c = tid & 3;
  int r2c = (tid + 512) >> 2, c2c = tid & 3;
  int tg0 = t0 + r0c - 2, tg1 = t0 + r1c - 2, tg2 = t0 + r2c - 2;
  bool v0 = (tg0 >= 0 && tg0 < 2048);
  bool v1 = (tg1 >= 0 && tg1 < 2048);
  bool v2 = (tid < 16) && (tg2 >= 0 && tg2 < 2048);
  h8v s0, s1, s2;

  // prologue: stage k0 = 0 into buffer 0
  s0 = v0 ? *(const h8v*)(Xb + (size_t)tg0 * 512 + c0c * 8) : zerov;
  s1 = v1 ? *(const h8v*)(Xb + (size_t)tg1 * 512 + c1c * 8) : zerov;
  s2 = v2 ? *(const h8v*)(Xb + (size_t)tg2 * 512 + c2c * 8) : zerov;
  *(h8v*)(&bsm[0][swb(r0c, c0c)]) = s0;
  *(h8v*)(&bsm[0][swb(r1c, c1c)]) = s1;
  if (tid < 16) *(h8v*)(&bsm[0][swb(r2c, c2c)]) = s2;
  __syncthreads();

  for (int kc = 0; kc < 16; ++kc) {
    int k0 = kc * 32;
    char* cb = bsm[kc & 1];
    bool pf = (kc < 15);
    if (pf) {
      int k1 = k0 + 32;
      s0 = v0 ? *(const h8v*)(Xb + (size_t)tg0 * 512 + k1 + c0c * 8) : zerov;
      s1 = v1 ? *(const h8v*)(Xb + (size_t)tg1 * 512 + k1 + c1c * 8) : zerov;
      s2 = v2 ? *(const h8v*)(Xb + (size_t)tg2 * 512 + k1 + c2c * 8) : zerov;
    }
#pragma unroll
    for (int s = 0; s < 5; ++s) {
      const _Float16* A = Mh + (size_t)s * 512 * 512 + (size_t)(o0 + wm) * 512 + k0 + koff;
      h8v a[2];
#pragma unroll
      for (int i = 0; i < 2; ++i)
        a[i] = *(const h8v*)(A + (size_t)(i * 16 + row16) * 512);
#pragma unroll
      for (int ni = 0; ni < 4; ++ni) {
        int rr = wn + ni * 16 + row16 + s;
        h8v bv = *(const h8v*)(&cb[swb(rr, kg)]);
#pragma unroll
        for (int mi = 0; mi < 2; ++mi)
          acc[mi][ni] = MFMA(a[mi], bv, acc[mi][ni]);
      }
    }
    if (pf) {
      char* nb = bsm[(kc & 1) ^ 1];
      *(h8v*)(&nb[swb(r0c, c0c)]) = s0;
      *(h8v*)(&nb[swb(r1c, c1c)]) = s1;
      if (tid < 16) *(h8v*)(&nb[swb(r2c, c2c)]) = s2;
    }
    __syncthreads();
  }

#pragma unroll
  for (int mi = 0; mi < 2; ++mi)
#pragma unroll
    for (int r = 0; r < 4; ++r) {
      int o = o0 + wm + mi * 16 + kg * 4 + r;
      float bias = zb[o];
#pragma unroll
      for (int ni = 0; ni < 4; ++ni) {
        int t = t0 + wn + ni * 16 + row16;
        float v = acc[mi][ni][r] + bias;
        x2ct[((size_t)b * 512 + o) * 2048 + t] = f2h(v);
        x2h[((size_t)b * 2048 + t) * 512 + o] = f2h(v);
      }
    }
}

// ---------------- K5: g/theta/phi projections
__global__ __launch_bounds__(256) void k_gtp(const _Float16* __restrict__ x2h,
                                             const _Float16* __restrict__ wth, const _Float16* __restrict__ wph,
                                             const _Float16* __restrict__ wg,
                                             const float* __restrict__ thb, const float* __restrict__ phb,
                                             const float* __restrict__ gb,
                                             _Float16* __restrict__ tht, _Float16* __restrict__ pht,
                                             _Float16* __restrict__ gv) {
  int b = blockIdx.z;
  int proj = blockIdx.y >> 1, dtile = blockIdx.y & 1;
  int wid = threadIdx.x >> 6, lane = threadIdx.x & 63;
  int wm = (wid >> 1) * 64, wn = (wid & 1) * 64;
  int row16 = lane & 15, kg = lane >> 4;
  const _Float16* X = x2h + (size_t)b * 2048 * 512;
  f4v acc[4][4];
#pragma unroll
  for (int mi = 0; mi < 4; ++mi)
#pragma unroll
    for (int ni = 0; ni < 4; ++ni) acc[mi][ni] = (f4v){0.f, 0.f, 0.f, 0.f};

  if (proj < 2) {
    const _Float16* W = (proj == 0) ? wth : wph;
    const float* bias = (proj == 0) ? thb : phb;
    _Float16* out = (proj == 0) ? tht : pht;
    int m0 = blockIdx.x * 128, n0 = dtile * 128;
    gemm64x64(X + (size_t)(m0 + wm) * 512, 512, W + (size_t)(n0 + wn) * 512, 512, 512, lane, acc);
#pragma unroll
    for (int mi = 0; mi < 4; ++mi)
#pragma unroll
      for (int r = 0; r < 4; ++r) {
        int t = m0 + wm + mi * 16 + kg * 4 + r;
#pragma unroll
        for (int ni = 0; ni < 4; ++ni) {
          int d = n0 + wn + ni * 16 + row16;
          out[((size_t)b * 2048 + t) * 256 + d] = f2h(acc[mi][ni][r] + bias[d]);
        }
      }
  } else {
    int m0 = dtile * 128, n0 = blockIdx.x * 128;
    gemm64x64(wg + (size_t)(m0 + wm) * 512, 512, X + (size_t)(n0 + wn) * 512, 512, 512, lane, acc);
#pragma unroll
    for (int mi = 0; mi < 4; ++mi)
#pragma unroll
      for (int r = 0; r < 4; ++r) {
        int d = m0 + wm + mi * 16 + kg * 4 + r;
        float bias = gb[d];
#pragma unroll
        for (int ni = 0; ni < 4; ++ni) {
          int t = n0 + wn + ni * 16 + row16;
          gv[((size_t)b * 256 + d) * 2048 + t] = f2h(acc[mi][ni][r] + bias);
        }
      }
  }
}

// ---------------- K6: flash attention, LDS-staged K/V (double-buffered, XOR-swizzled)
__global__ __launch_bounds__(512) void k_attn(const _Float16* __restrict__ tht,
                                              const _Float16* __restrict__ pht,
                                              const _Float16* __restrict__ gv,
                                              _Float16* __restrict__ yp,
                                              float* __restrict__ mlm, float* __restrict__ mll) {
  int b = blockIdx.z, sp = blockIdx.y;
  int tid = threadIdx.x;
  int wid = tid >> 6, lane = tid & 63;
  int q0 = blockIdx.x * 128 + wid * 16;
  int row16 = lane & 15, kg = lane >> 4, koff = kg * 8;
  int rswz = row16 & 7;

  __shared__ __align__(16) _Float16 kvbuf[2][32768];   // 2 x 64 KB
  __shared__ __align__(16) _Float16 p_lds[8][1024];    // per-wave 16x64 f16, XOR-swizzled
  char* pw = (char*)&p_lds[wid][0];

  const _Float16* thb = tht + (size_t)b * 2048 * 256;
  const _Float16* phb = pht + (size_t)b * 2048 * 256;
  const _Float16* gvb = gv + (size_t)b * 256 * 2048;

  h8v qf[8];
#pragma unroll
  for (int ks = 0; ks < 8; ++ks)
    qf[ks] = *(const h8v*)(thb + (size_t)(q0 + row16) * 256 + ks * 32 + koff);

  float m_i[4], l_i[4];
#pragma unroll
  for (int r = 0; r < 4; ++r) { m_i[r] = -3e38f; l_i[r] = 0.f; }
  f4v yacc[16];
#pragma unroll
  for (int ni = 0; ni < 16; ++ni) yacc[ni] = (f4v){0.f, 0.f, 0.f, 0.f};

  {
    int k0 = sp * 1024;
#pragma unroll
    for (int j = 0; j < 4; ++j) {
      int idx = tid + 512 * j;
      h8v kv = *(const h8v*)(phb + (size_t)(k0 + (idx >> 5)) * 256 + (idx & 31) * 8);
      h8v vv = *(const h8v*)(gvb + (size_t)(idx >> 3) * 2048 + k0 + (idx & 7) * 8);
      *(h8v*)((char*)&kvbuf[0][0] + (idx >> 5) * 512 + (((idx & 31) ^ ((idx >> 5) & 7)) << 4)) = kv;
      *(h8v*)((char*)&kvbuf[0][0] + 32768 + (idx >> 3) * 128 + (((idx & 7) ^ ((idx >> 3) & 7)) << 4)) = vv;
    }
  }
  __syncthreads();

  for (int t = 0; t < 16; ++t) {
    int k0 = sp * 1024 + t * 64;
    char* cb = (char*)&kvbuf[t & 1][0];
    char* nb = (char*)&kvbuf[(t & 1) ^ 1][0];

    h8v kreg[4], vreg[4];
    bool pf = (t < 15);
    if (pf) {
      int k1 = k0 + 64;
#pragma unroll
      for (int j = 0; j < 4; ++j) {
        int idx = tid + 512 * j;
        kreg[j] = *(const h8v*)(phb + (size_t)(k1 + (idx >> 5)) * 256 + (idx & 31) * 8);
        vreg[j] = *(const h8v*)(gvb + (size_t)(idx >> 3) * 2048 + k1 + (idx & 7) * 8);
      }
    }

    f4v sacc[4];
#pragma unroll
    for (int ni = 0; ni < 4; ++ni) sacc[ni] = (f4v){0.f, 0.f, 0.f, 0.f};
#pragma unroll
    for (int ks = 0; ks < 8; ++ks) {
#pragma unroll
      for (int ni = 0; ni < 4; ++ni) {
        int krow = ni * 16 + row16;
        h8v kf = *(const h8v*)(cb + krow * 512 + ((((ks << 2) | kg) ^ rswz) << 4));
        sacc[ni] = MFMA(qf[ks], kf, sacc[ni]);
      }
    }
    float al[4];
#pragma unroll
    for (int r = 0; r < 4; ++r) {
      float rm = fmaxf(fmaxf(sacc[0][r], sacc[1][r]), fmaxf(sacc[2][r], sacc[3][r]));
#pragma unroll
      for (int m = 1; m <= 8; m <<= 1) rm = fmaxf(rm, __shfl_xor(rm, m, 64));
      float mn = fmaxf(m_i[r], rm);
      al[r] = __expf(m_i[r] - mn);
      m_i[r] = mn;
      float rs = 0.f;
#pragma unroll
      for (int ni = 0; ni < 4; ++ni) {
        float p = __expf(sacc[ni][r] - mn);
        sacc[ni][r] = p;
        rs += p;
      }
#pragma unroll
      for (int m = 1; m <= 8; m <<= 1) rs += __shfl_xor(rs, m, 64);
      l_i[r] = l_i[r] * al[r] + rs;
    }
#pragma unroll
    for (int r = 0; r < 4; ++r) {
      int q = kg * 4 + r;
#pragma unroll
      for (int ni = 0; ni < 4; ++ni) {
        int sx = ni * 16 + row16;
        int byte = (q * 128 + sx * 2) ^ ((q & 7) << 4);
        *(_Float16*)(pw + byte) = f2h(sacc[ni][r]);
      }
    }
#pragma unroll
    for (int ni = 0; ni < 16; ++ni)
#pragma unroll
      for (int r = 0; r < 4; ++r) yacc[ni][r] *= al[r];
#pragma unroll
    for (int ks2 = 0; ks2 < 2; ++ks2) {
      int pbyte = (row16 * 128 + (ks2 * 32 + koff) * 2) ^ (rswz << 4);
      h8v pa = *(const h8v*)(pw + pbyte);
#pragma unroll
      for (int ni = 0; ni < 16; ++ni) {
        int d = ni * 16 + row16;
        h8v vb = *(const h8v*)(cb + 32768 + d * 128 + ((((ks2 << 2) | kg) ^ rswz) << 4));
        yacc[ni] = MFMA(pa, vb, yacc[ni]);
      }
    }
    if (pf) {
#pragma unroll
      for (int j = 0; j < 4; ++j) {
        int idx = tid + 512 * j;
        *(h8v*)(nb + (idx >> 5) * 512 + (((idx & 31) ^ ((idx >> 5) & 7)) << 4)) = kreg[j];
        *(h8v*)(nb + 32768 + (idx >> 3) * 128 + (((idx & 7) ^ ((idx >> 3) & 7)) << 4)) = vreg[j];
      }
    }
    __syncthreads();
  }

  _Float16* yb = yp + (size_t)(sp * 8 + b) * 2048 * 256;
  float* mm = mlm + (size_t)(sp * 8 + b) * 2048;
  float* ml = mll + (size_t)(sp * 8 + b) * 2048;
#pragma unroll
  for (int r = 0; r < 4; ++r) {
    int q = q0 + kg * 4 + r;
#pragma unroll
    for (int ni = 0; ni < 16; ++ni)
      yb[(size_t)q * 256 + ni * 16 + row16] = f2h(yacc[ni][r]);
    if (row16 == 0) { mm[q] = m_i[r]; ml[q] = l_i[r]; }
  }
}

// ---------------- K6b: combine KV splits
__global__ __launch_bounds__(256) void k_comb(const _Float16* __restrict__ yp,
                                              const float* __restrict__ mlm, const float* __restrict__ mll,
                                              _Float16* __restrict__ yv) {
  int b = blockIdx.y;
  int q = blockIdx.x * 32 + (threadIdx.x >> 3);
  int d0 = (threadIdx.x & 7) * 32;
  float ms[NSPLIT], w[NSPLIT];
  float M = -3e38f;
#pragma unroll
  for (int s = 0; s < NSPLIT; ++s) {
    ms[s] = mlm[(size_t)(s * 8 + b) * 2048 + q];
    M = fmaxf(M, ms[s]);
  }
  float L = 0.f;
#pragma unroll
  for (int s = 0; s < NSPLIT; ++s) {
    w[s] = __expf(ms[s] - M);
    L += w[s] * mll[(size_t)(s * 8 + b) * 2048 + q];
  }
  float inv = 1.f / L;
#pragma unroll
  for (int s = 0; s < NSPLIT; ++s) w[s] *= inv;
  _Float16* out = yv + ((size_t)b * 2048 + q) * 256 + d0;
#pragma unroll
  for (int c = 0; c < 4; ++c) {
    float o[8];
#pragma unroll
    for (int j = 0; j < 8; ++j) o[j] = 0.f;
#pragma unroll
    for (int s = 0; s < NSPLIT; ++s) {
      h8v v = *(const h8v*)(yp + ((size_t)(s * 8 + b) * 2048 + q) * 256 + d0 + c * 8);
#pragma unroll
      for (int j = 0; j < 8; ++j) o[j] += w[s] * (float)v[j];
    }
    h8v ov;
#pragma unroll
    for (int j = 0; j < 8; ++j) ov[j] = f2h(o[j]);
    *(h8v*)(out + c * 8) = ov;
  }
}

// ---------------- K7: out = BN(W@y + Wb) + x2 (residual f16)
__global__ __launch_bounds__(256) void k_final(const _Float16* __restrict__ Wh,
                                               const _Float16* __restrict__ yv,
                                               const float* __restrict__ Wb,
                                               const float* __restrict__ bng, const float* __restrict__ bnb,
                                               const float* __restrict__ bnm, const float* __restrict__ bnv,
                                               const _Float16* __restrict__ x2ct, float* __restrict__ out) {
  int b = blockIdx.z;
  int o0 = blockIdx.y * 128, t0 = blockIdx.x * 128;
  int wid = threadIdx.x >> 6, lane = threadIdx.x & 63;
  int wm = (wid >> 1) * 64, wn = (wid & 1) * 64;
  int row16 = lane & 15, kg = lane >> 4;
  f4v acc[4][4];
#pragma unroll
  for (int mi = 0; mi < 4; ++mi)
#pragma unroll
    for (int ni = 0; ni < 4; ++ni) acc[mi][ni] = (f4v){0.f, 0.f, 0.f, 0.f};
  gemm64x64(Wh + (size_t)(o0 + wm) * 256, 256,
            yv + (size_t)b * 2048 * 256 + (size_t)(t0 + wn) * 256, 256, 256, lane, acc);
#pragma unroll
  for (int mi = 0; mi < 4; ++mi)
#pragma unroll
    for (int r = 0; r < 4; ++r) {
      int o = o0 + wm + mi * 16 + kg * 4 + r;
      float sc = bng[o] * rsqrtf(bnv[o] + 1e-5f);
      float add = (Wb[o] - bnm[o]) * sc + bnb[o];
#pragma unroll
      for (int ni = 0; ni < 4; ++ni) {
        int t = t0 + wn + ni * 16 + row16;
        size_t idx = ((size_t)b * 512 + o) * 2048 + t;
        out[idx] = acc[mi][ni][r] * sc + add + (float)x2ct[idx];
      }
    }
}

extern "C" void kernel_launch(void* const* d_in, const int* in_sizes, int n_in,
                              void* d_out, int out_size, void* d_ws, size_t ws_size,
                              hipStream_t stream) {
  const float* x    = (const float*)d_in[0];
  const float* tcw1 = (const float*)d_in[1];
  const float* tcw2 = (const float*)d_in[2];
  const float* zw   = (const float*)d_in[3];
  const float* zb   = (const float*)d_in[4];
  const float* gw   = (const float*)d_in[5];
  const float* gb   = (const float*)d_in[6];
  const float* thw  = (const float*)d_in[7];
  const float* thb  = (const float*)d_in[8];
  const float* phw  = (const float*)d_in[9];
  const float* phb  = (const float*)d_in[10];
  const float* Ww   = (const float*)d_in[11];
  const float* Wb   = (const float*)d_in[12];
  const float* bng  = (const float*)d_in[13];
  const float* bnb  = (const float*)d_in[14];
  const float* bnm  = (const float*)d_in[15];
  const float* bnv  = (const float*)d_in[16];

  char* Wp = (char*)d_ws;
  _Float16* xpe = (_Float16*)(Wp);                  // [b][t][c] f16      16,777,216 B
  _Float16* Mh  = (_Float16*)(Wp + 16777216);       // [5][o][c] f16       2,621,440
  _Float16* x2h = (_Float16*)(Wp + 19398656);       // [b][t][c] f16      16,777,216
  _Float16* x2c = (_Float16*)(Wp + 36175872);       // [b][c][t] f16      16,777,216
  _Float16* tht = (_Float16*)(Wp + 69730304);       // [b][t][d] f16       8,388,608
  _Float16* pht = (_Float16*)(Wp + 78118912);       // [b][t][d] f16       8,388,608
  _Float16* gv  = (_Float16*)(Wp + 86507520);       // [b][d][t] f16       8,388,608
  _Float16* yv  = (_Float16*)(Wp + 94896128);       // [b][t][d] f16       8,388,608
  _Float16* wc  = (_Float16*)(Wp + 103284736);      // 4 x 131072 f16      1,048,576
  _Float16* wth = wc, *wph = wc + 131072, *wg = wc + 262144, *wW = wc + 393216;
  // merge scratch aliases x2c region (dead until k_conv, which runs after k_merge)
  _Float16* zh  = (_Float16*)(Wp + 36175872);                // 512x1536 f16  1,572,864 B
  _Float16* wt  = (_Float16*)(Wp + 36175872 + 1572864);      // 6x512x512 f16 3,145,728 B
  // attention split scratch aliases xpe/Mh region (dead after k_gtp)
  _Float16* yp  = (_Float16*)(Wp);                  // 2x8x2048x256 f16   16,777,216 B
  float*    mlm = (float*)   (Wp + 16777216);       // 2x8x2048 f32          131,072
  float*    mll = (float*)   (Wp + 16908288);       // 2x8x2048 f32          131,072

  k_cast  <<<dim3(512, 4), 256, 0, stream>>>(thw, phw, gw, Ww, wc);
  k_castz <<<3072, 256, 0, stream>>>(zw, zh);
  k_wtrans<<<dim3(8, 8, 6), 256, 0, stream>>>(tcw1, tcw2, wt);
  k_merge <<<dim3(8, 8, 5), 256, 0, stream>>>(zh, wt, zw, Mh);
  k_pe_t  <<<dim3(64, 16, 8), 256, 0, stream>>>(x, xpe);
  k_conv  <<<dim3(16, 8, 8), 256, 0, stream>>>(Mh, xpe, zb, x2c, x2h);
  k_gtp   <<<dim3(16, 6, 8), 256, 0, stream>>>(x2h, wth, wph, wg, thb, phb, gb, tht, pht, gv);
  k_attn  <<<dim3(16, NSPLIT, 8), 512, 0, stream>>>(tht, pht, gv, yp, mlm, mll);
  k_comb  <<<dim3(64, 8), 256, 0, stream>>>(yp, mlm, mll, yv);
  k_final <<<dim3(16, 4, 8), 256, 0, stream>>>(wW, yv, Wb, bng, bnb, bnm, bnv, x2c, (float*)d_out);
}

// Round 10
// 221.832 us; speedup vs baseline: 1.3268x; 1.3268x over previous
//
#include <hip/hip_runtime.h>
#include <stdint.h>

typedef _Float16 h8v __attribute__((ext_vector_type(8)));
typedef float f4v __attribute__((ext_vector_type(4)));

#define MFMA(a,b,c) __builtin_amdgcn_mfma_f32_16x16x32_f16((a),(b),(c),0,0,0)
#define NSPLIT 2

__device__ __forceinline__ _Float16 f2h(float f) { return (_Float16)f; }

// swizzled byte offset: row pitch 64B, 4 chunks of 16B, XOR on (row>>1)&3
__device__ __forceinline__ int swb(int row, int chunk) {
  return row * 64 + (((chunk) ^ ((row >> 1) & 3)) << 4);
}

// ---------------- K1: PE add + transpose:  xpe_t[b][t][c] = f16(x[b][c][t] + pe(t,c))
__global__ __launch_bounds__(256) void k_pe_t(const float* __restrict__ x, _Float16* __restrict__ xpe) {
  __shared__ float tile[32][33];
  int b = blockIdx.z;
  int t0 = blockIdx.x * 32, c0 = blockIdx.y * 32;
  int tid = threadIdx.x;
  int col = tid & 31, rowq = tid >> 5;
#pragma unroll
  for (int i = 0; i < 4; ++i) {
    int c = c0 + rowq + i * 8;
    int t = t0 + col;
    int j2 = c & ~1;
    float dv = expf(-0.01798894603885192f * (float)j2);  // ln(1e4)/512
    float ang = (float)t * dv;
    float pe = (c & 1) ? cosf(ang) : sinf(ang);
    tile[rowq + i * 8][col] = x[((size_t)b * 512 + c) * 2048 + t] + pe;
  }
  __syncthreads();
#pragma unroll
  for (int i = 0; i < 4; ++i) {
    int t = t0 + rowq + i * 8;
    int c = c0 + col;
    xpe[((size_t)b * 2048 + t) * 512 + c] = f2h(tile[col][rowq + i * 8]);
  }
}

// ---------------- K2a: cast projection weights to f16
__global__ __launch_bounds__(256) void k_cast(const float* __restrict__ a0, const float* __restrict__ a1,
                                              const float* __restrict__ a2, const float* __restrict__ a3,
                                              _Float16* __restrict__ o) {
  int w = blockIdx.y;
  const float* s = (w == 0) ? a0 : (w == 1) ? a1 : (w == 2) ? a2 : a3;
  int i = blockIdx.x * 256 + threadIdx.x;
  o[(size_t)w * 131072 + i] = f2h(s[i]);
}

// ---------------- K2b: cast z_w (512x1536) to f16
__global__ __launch_bounds__(256) void k_castz(const float* __restrict__ zw, _Float16* __restrict__ zh) {
  int i = blockIdx.x * 256 + threadIdx.x;
  zh[i] = f2h(zw[i]);
}

// ---------------- K2c: transpose-cast temporal conv weights
__global__ __launch_bounds__(256) void k_wtrans(const float* __restrict__ w1, const float* __restrict__ w2,
                                                _Float16* __restrict__ wt) {
  int z = blockIdx.z;
  const float* src = (z < 3) ? w1 : w2;
  int k = (z < 3) ? z : z - 3;
  __shared__ _Float16 tile[64][65];
  int m0 = blockIdx.y * 64, c0 = blockIdx.x * 64;
  int tid = threadIdx.x;
  int tc = tid & 63, tm = tid >> 6;
#pragma unroll
  for (int i = 0; i < 16; ++i) {
    int m = m0 + tm + i * 4;
    tile[tm + i * 4][tc] = f2h(src[(size_t)m * 1536 + (size_t)k * 512 + c0 + tc]);
  }
  __syncthreads();
#pragma unroll
  for (int i = 0; i < 16; ++i) {
    int c = c0 + tm + i * 4;
    wt[((size_t)z * 512 + c) * 512 + m0 + tc] = tile[tc][tm + i * 4];
  }
}

// ---------------- K3: merge conv weights through z (f16 MFMA)
__global__ __launch_bounds__(256) void k_merge(const _Float16* __restrict__ zh,
                                               const _Float16* __restrict__ wt,
                                               const float* __restrict__ zwf,
                                               _Float16* __restrict__ M) {
  int s = blockIdx.z;
  int wid = threadIdx.x >> 6, lane = threadIdx.x & 63;
  int o0 = blockIdx.y * 64 + (wid >> 1) * 32;
  int c0 = blockIdx.x * 64 + (wid & 1) * 32;
  int row16 = lane & 15, kg = lane >> 4, koff = kg * 8;
  f4v acc[2][2];
#pragma unroll
  for (int mi = 0; mi < 2; ++mi)
#pragma unroll
    for (int ni = 0; ni < 2; ++ni) acc[mi][ni] = (f4v){0.f, 0.f, 0.f, 0.f};

  int np = (s == 2) ? 2 : 1;
  for (int p = 0; p < np; ++p) {
    int seg, wi;
    if (s == 0)      { seg = 1024; wi = 3; }
    else if (s == 1) { seg = 512;  wi = 0; }
    else if (s == 3) { seg = 512;  wi = 2; }
    else if (s == 4) { seg = 1024; wi = 5; }
    else             { seg = (p == 0) ? 512 : 1024; wi = (p == 0) ? 1 : 4; }
    const _Float16* A = zh + seg;
    const _Float16* B = wt + (size_t)wi * 512 * 512;
    for (int k0 = 0; k0 < 512; k0 += 32) {
      h8v a[2], bv[2];
#pragma unroll
      for (int i = 0; i < 2; ++i)
        a[i] = *(const h8v*)(A + (size_t)(o0 + i * 16 + row16) * 1536 + k0 + koff);
#pragma unroll
      for (int i = 0; i < 2; ++i)
        bv[i] = *(const h8v*)(B + (size_t)(c0 + i * 16 + row16) * 512 + k0 + koff);
#pragma unroll
      for (int mi = 0; mi < 2; ++mi)
#pragma unroll
        for (int ni = 0; ni < 2; ++ni)
          acc[mi][ni] = MFMA(a[mi], bv[ni], acc[mi][ni]);
    }
  }
  _Float16* dst = M + (size_t)s * 512 * 512;
#pragma unroll
  for (int mi = 0; mi < 2; ++mi)
#pragma unroll
    for (int r = 0; r < 4; ++r) {
      int o = o0 + mi * 16 + kg * 4 + r;
#pragma unroll
      for (int ni = 0; ni < 2; ++ni) {
        int c = c0 + ni * 16 + row16;
        float v = acc[mi][ni][r];
        if (s == 2) v += zwf[(size_t)o * 1536 + c];
        dst[(size_t)o * 512 + c] = f2h(v);
      }
    }
}

// ---------------- shared LDS-staged 128x128 TN GEMM (both operands staged, coalesced)
// L[128 rows][K] row-major stride ldl; R[128 rows][K] stride ldr. 256 threads, 4 waves.
__device__ __forceinline__ void gemm128_lds(const _Float16* __restrict__ L, int ldl,
                                            const _Float16* __restrict__ R, int ldr,
                                            int K, int tid, char* lsA, char* lsB,
                                            f4v acc[4][4]) {
  int wid = tid >> 6, lane = tid & 63;
  int wm = (wid >> 1) * 64, wn = (wid & 1) * 64;
  int row16 = lane & 15, kg = lane >> 4;
  int ar0 = tid >> 2, ar1 = (tid + 256) >> 2, ach = tid & 3;
  h8v pa0, pa1, pb0, pb1;

  pa0 = *(const h8v*)(L + (size_t)ar0 * ldl + ach * 8);
  pa1 = *(const h8v*)(L + (size_t)ar1 * ldl + ach * 8);
  pb0 = *(const h8v*)(R + (size_t)ar0 * ldr + ach * 8);
  pb1 = *(const h8v*)(R + (size_t)ar1 * ldr + ach * 8);
  *(h8v*)(lsA + swb(ar0, ach)) = pa0;
  *(h8v*)(lsA + swb(ar1, ach)) = pa1;
  *(h8v*)(lsB + swb(ar0, ach)) = pb0;
  *(h8v*)(lsB + swb(ar1, ach)) = pb1;
  __syncthreads();

  int nk = K >> 5;
  for (int kc = 0; kc < nk; ++kc) {
    char* ca = lsA + (kc & 1) * 8192;
    char* cb = lsB + (kc & 1) * 8192;
    bool pf = (kc < nk - 1);
    if (pf) {
      int k1 = (kc + 1) << 5;
      pa0 = *(const h8v*)(L + (size_t)ar0 * ldl + k1 + ach * 8);
      pa1 = *(const h8v*)(L + (size_t)ar1 * ldl + k1 + ach * 8);
      pb0 = *(const h8v*)(R + (size_t)ar0 * ldr + k1 + ach * 8);
      pb1 = *(const h8v*)(R + (size_t)ar1 * ldr + k1 + ach * 8);
    }
    h8v a[4], bv[4];
#pragma unroll
    for (int i = 0; i < 4; ++i)
      a[i] = *(const h8v*)(ca + swb(wm + i * 16 + row16, kg));
#pragma unroll
    for (int i = 0; i < 4; ++i)
      bv[i] = *(const h8v*)(cb + swb(wn + i * 16 + row16, kg));
#pragma unroll
    for (int mi = 0; mi < 4; ++mi)
#pragma unroll
      for (int ni = 0; ni < 4; ++ni)
        acc[mi][ni] = MFMA(a[mi], bv[ni], acc[mi][ni]);
    if (pf) {
      char* na = lsA + ((kc & 1) ^ 1) * 8192;
      char* nb = lsB + ((kc & 1) ^ 1) * 8192;
      *(h8v*)(na + swb(ar0, ach)) = pa0;
      *(h8v*)(na + swb(ar1, ach)) = pa1;
      *(h8v*)(nb + swb(ar0, ach)) = pb0;
      *(h8v*)(nb + swb(ar1, ach)) = pb1;
    }
    __syncthreads();
  }
}

// ---------------- K4: conv GEMM  x2[o][t] = sum_s M_s[o][:]·xpe[t+s-2][:] + zb
// tile 64(o) x 128(t); BOTH operands LDS-staged coalesced; A: 320 rows (5 shifts x 64 o), B: 132 rows halo
__global__ __launch_bounds__(256, 2) void k_conv(const _Float16* __restrict__ Mh,
                                                 const _Float16* __restrict__ xpe,
                                                 const float* __restrict__ zb,
                                                 _Float16* __restrict__ x2ct,
                                                 _Float16* __restrict__ x2h) {
  int b = blockIdx.z;
  int o0 = blockIdx.y * 64, t0 = blockIdx.x * 128;
  int tid = threadIdx.x;
  int wid = tid >> 6, lane = tid & 63;
  int wm = (wid >> 1) * 32, wn = (wid & 1) * 64;
  int row16 = lane & 15, kg = lane >> 4;
  __shared__ __align__(16) char asm2[2][320 * 64];  // 2 x 20 KB
  __shared__ __align__(16) char bsm[2][132 * 64];   // 2 x 8.25 KB
  const _Float16* Xb = xpe + (size_t)b * 2048 * 512;
  const h8v zerov = {0, 0, 0, 0, 0, 0, 0, 0};

  f4v acc[2][4];
#pragma unroll
  for (int mi = 0; mi < 2; ++mi)
#pragma unroll
    for (int ni = 0; ni < 4; ++ni) acc[mi][ni] = (f4v){0.f, 0.f, 0.f, 0.f};

  // A staging: 1280 chunks (5 per thread); row = s*64+orow, chunk = 16B col
  int arow[5], asrow[5], aorow[5], achk = tid & 3;
#pragma unroll
  for (int j = 0; j < 5; ++j) {
    arow[j] = (tid + 256 * j) >> 2;        // 0..319
    asrow[j] = arow[j] >> 6;               // shift s
    aorow[j] = arow[j] & 63;               // o-row within tile
  }
  // B staging: 528 chunks; rows 0..131 with halo -2
  int br0 = tid >> 2, br1 = (tid + 256) >> 2, br2 = (tid + 512) >> 2;
  int tg0 = t0 + br0 - 2, tg1 = t0 + br1 - 2, tg2 = t0 + br2 - 2;
  bool v0 = (tg0 >= 0 && tg0 < 2048);
  bool v1 = (tg1 >= 0 && tg1 < 2048);
  bool v2 = (tid < 16) && (tg2 >= 0 && tg2 < 2048);
  h8v sa[5], s0, s1, s2;

  // prologue: stage k0 = 0
#pragma unroll
  for (int j = 0; j < 5; ++j)
    sa[j] = *(const h8v*)(Mh + (size_t)asrow[j] * 262144 + (size_t)(o0 + aorow[j]) * 512 + achk * 8);
  s0 = v0 ? *(const h8v*)(Xb + (size_t)tg0 * 512 + achk * 8) : zerov;
  s1 = v1 ? *(const h8v*)(Xb + (size_t)tg1 * 512 + achk * 8) : zerov;
  s2 = v2 ? *(const h8v*)(Xb + (size_t)tg2 * 512 + achk * 8) : zerov;
#pragma unroll
  for (int j = 0; j < 5; ++j) *(h8v*)(&asm2[0][swb(arow[j], achk)]) = sa[j];
  *(h8v*)(&bsm[0][swb(br0, achk)]) = s0;
  *(h8v*)(&bsm[0][swb(br1, achk)]) = s1;
  if (tid < 16) *(h8v*)(&bsm[0][swb(br2, achk)]) = s2;
  __syncthreads();

  for (int kc = 0; kc < 16; ++kc) {
    char* ca = asm2[kc & 1];
    char* cb = bsm[kc & 1];
    bool pf = (kc < 15);
    if (pf) {
      int k1 = (kc + 1) * 32;
#pragma unroll
      for (int j = 0; j < 5; ++j)
        sa[j] = *(const h8v*)(Mh + (size_t)asrow[j] * 262144 + (size_t)(o0 + aorow[j]) * 512 + k1 + achk * 8);
      s0 = v0 ? *(const h8v*)(Xb + (size_t)tg0 * 512 + k1 + achk * 8) : zerov;
      s1 = v1 ? *(const h8v*)(Xb + (size_t)tg1 * 512 + k1 + achk * 8) : zerov;
      s2 = v2 ? *(const h8v*)(Xb + (size_t)tg2 * 512 + k1 + achk * 8) : zerov;
    }
#pragma unroll
    for (int s = 0; s < 5; ++s) {
      h8v a[2];
#pragma unroll
      for (int i = 0; i < 2; ++i)
        a[i] = *(const h8v*)(ca + swb(s * 64 + wm + i * 16 + row16, kg));
#pragma unroll
      for (int ni = 0; ni < 4; ++ni) {
        int rr = wn + ni * 16 + row16 + s;
        h8v bv = *(const h8v*)(cb + swb(rr, kg));
#pragma unroll
        for (int mi = 0; mi < 2; ++mi)
          acc[mi][ni] = MFMA(a[mi], bv, acc[mi][ni]);
      }
    }
    if (pf) {
      char* na = asm2[(kc & 1) ^ 1];
      char* nb = bsm[(kc & 1) ^ 1];
#pragma unroll
      for (int j = 0; j < 5; ++j) *(h8v*)(&na[swb(arow[j], achk)]) = sa[j];
      *(h8v*)(&nb[swb(br0, achk)]) = s0;
      *(h8v*)(&nb[swb(br1, achk)]) = s1;
      if (tid < 16) *(h8v*)(&nb[swb(br2, achk)]) = s2;
    }
    __syncthreads();
  }

#pragma unroll
  for (int mi = 0; mi < 2; ++mi)
#pragma unroll
    for (int r = 0; r < 4; ++r) {
      int o = o0 + wm + mi * 16 + kg * 4 + r;
      float bias = zb[o];
#pragma unroll
      for (int ni = 0; ni < 4; ++ni) {
        int t = t0 + wn + ni * 16 + row16;
        float v = acc[mi][ni][r] + bias;
        x2ct[((size_t)b * 512 + o) * 2048 + t] = f2h(v);
        x2h[((size_t)b * 2048 + t) * 512 + o] = f2h(v);
      }
    }
}

// ---------------- K5: g/theta/phi projections (LDS-staged GEMM core)
__global__ __launch_bounds__(256, 3) void k_gtp(const _Float16* __restrict__ x2h,
                                                const _Float16* __restrict__ wth, const _Float16* __restrict__ wph,
                                                const _Float16* __restrict__ wg,
                                                const float* __restrict__ thb, const float* __restrict__ phb,
                                                const float* __restrict__ gb,
                                                _Float16* __restrict__ tht, _Float16* __restrict__ pht,
                                                _Float16* __restrict__ gv) {
  int b = blockIdx.z;
  int proj = blockIdx.y >> 1, dtile = blockIdx.y & 1;
  int tid = threadIdx.x;
  int wid = tid >> 6, lane = tid & 63;
  int wm = (wid >> 1) * 64, wn = (wid & 1) * 64;
  int row16 = lane & 15, kg = lane >> 4;
  __shared__ __align__(16) char lA[2][8192];
  __shared__ __align__(16) char lB[2][8192];
  const _Float16* X = x2h + (size_t)b * 2048 * 512;
  f4v acc[4][4];
#pragma unroll
  for (int mi = 0; mi < 4; ++mi)
#pragma unroll
    for (int ni = 0; ni < 4; ++ni) acc[mi][ni] = (f4v){0.f, 0.f, 0.f, 0.f};

  if (proj < 2) {
    const _Float16* W = (proj == 0) ? wth : wph;
    const float* bias = (proj == 0) ? thb : phb;
    _Float16* out = (proj == 0) ? tht : pht;
    int m0 = blockIdx.x * 128, n0 = dtile * 128;
    gemm128_lds(X + (size_t)m0 * 512, 512, W + (size_t)n0 * 512, 512, 512, tid, lA[0], lB[0], acc);
#pragma unroll
    for (int mi = 0; mi < 4; ++mi)
#pragma unroll
      for (int r = 0; r < 4; ++r) {
        int t = m0 + wm + mi * 16 + kg * 4 + r;
#pragma unroll
        for (int ni = 0; ni < 4; ++ni) {
          int d = n0 + wn + ni * 16 + row16;
          out[((size_t)b * 2048 + t) * 256 + d] = f2h(acc[mi][ni][r] + bias[d]);
        }
      }
  } else {
    int m0 = dtile * 128, n0 = blockIdx.x * 128;
    gemm128_lds(wg + (size_t)m0 * 512, 512, X + (size_t)n0 * 512, 512, 512, tid, lA[0], lB[0], acc);
#pragma unroll
    for (int mi = 0; mi < 4; ++mi)
#pragma unroll
      for (int r = 0; r < 4; ++r) {
        int d = m0 + wm + mi * 16 + kg * 4 + r;
        float bias = gb[d];
#pragma unroll
        for (int ni = 0; ni < 4; ++ni) {
          int t = n0 + wn + ni * 16 + row16;
          gv[((size_t)b * 256 + d) * 2048 + t] = f2h(acc[mi][ni][r] + bias);
        }
      }
  }
}

// ---------------- K6: flash attention, LDS-staged K/V (double-buffered, XOR-swizzled)
__global__ __launch_bounds__(512) void k_attn(const _Float16* __restrict__ tht,
                                              const _Float16* __restrict__ pht,
                                              const _Float16* __restrict__ gv,
                                              _Float16* __restrict__ yp,
                                              float* __restrict__ mlm, float* __restrict__ mll) {
  int b = blockIdx.z, sp = blockIdx.y;
  int tid = threadIdx.x;
  int wid = tid >> 6, lane = tid & 63;
  int q0 = blockIdx.x * 128 + wid * 16;
  int row16 = lane & 15, kg = lane >> 4, koff = kg * 8;
  int rswz = row16 & 7;

  __shared__ __align__(16) _Float16 kvbuf[2][32768];
  __shared__ __align__(16) _Float16 p_lds[8][1024];
  char* pw = (char*)&p_lds[wid][0];

  const _Float16* thb = tht + (size_t)b * 2048 * 256;
  const _Float16* phb = pht + (size_t)b * 2048 * 256;
  const _Float16* gvb = gv + (size_t)b * 256 * 2048;

  h8v qf[8];
#pragma unroll
  for (int ks = 0; ks < 8; ++ks)
    qf[ks] = *(const h8v*)(thb + (size_t)(q0 + row16) * 256 + ks * 32 + koff);

  float m_i[4], l_i[4];
#pragma unroll
  for (int r = 0; r < 4; ++r) { m_i[r] = -3e38f; l_i[r] = 0.f; }
  f4v yacc[16];
#pragma unroll
  for (int ni = 0; ni < 16; ++ni) yacc[ni] = (f4v){0.f, 0.f, 0.f, 0.f};

  {
    int k0 = sp * 1024;
#pragma unroll
    for (int j = 0; j < 4; ++j) {
      int idx = tid + 512 * j;
      h8v kv = *(const h8v*)(phb + (size_t)(k0 + (idx >> 5)) * 256 + (idx & 31) * 8);
      h8v vv = *(const h8v*)(gvb + (size_t)(idx >> 3) * 2048 + k0 + (idx & 7) * 8);
      *(h8v*)((char*)&kvbuf[0][0] + (idx >> 5) * 512 + (((idx & 31) ^ ((idx >> 5) & 7)) << 4)) = kv;
      *(h8v*)((char*)&kvbuf[0][0] + 32768 + (idx >> 3) * 128 + (((idx & 7) ^ ((idx >> 3) & 7)) << 4)) = vv;
    }
  }
  __syncthreads();

  for (int t = 0; t < 16; ++t) {
    int k0 = sp * 1024 + t * 64;
    char* cb = (char*)&kvbuf[t & 1][0];
    char* nb = (char*)&kvbuf[(t & 1) ^ 1][0];

    h8v kreg[4], vreg[4];
    bool pf = (t < 15);
    if (pf) {
      int k1 = k0 + 64;
#pragma unroll
      for (int j = 0; j < 4; ++j) {
        int idx = tid + 512 * j;
        kreg[j] = *(const h8v*)(phb + (size_t)(k1 + (idx >> 5)) * 256 + (idx & 31) * 8);
        vreg[j] = *(const h8v*)(gvb + (size_t)(idx >> 3) * 2048 + k1 + (idx & 7) * 8);
      }
    }

    f4v sacc[4];
#pragma unroll
    for (int ni = 0; ni < 4; ++ni) sacc[ni] = (f4v){0.f, 0.f, 0.f, 0.f};
#pragma unroll
    for (int ks = 0; ks < 8; ++ks) {
#pragma unroll
      for (int ni = 0; ni < 4; ++ni) {
        int krow = ni * 16 + row16;
        h8v kf = *(const h8v*)(cb + krow * 512 + ((((ks << 2) | kg) ^ rswz) << 4));
        sacc[ni] = MFMA(qf[ks], kf, sacc[ni]);
      }
    }
    float al[4];
#pragma unroll
    for (int r = 0; r < 4; ++r) {
      float rm = fmaxf(fmaxf(sacc[0][r], sacc[1][r]), fmaxf(sacc[2][r], sacc[3][r]));
#pragma unroll
      for (int m = 1; m <= 8; m <<= 1) rm = fmaxf(rm, __shfl_xor(rm, m, 64));
      float mn = fmaxf(m_i[r], rm);
      al[r] = __expf(m_i[r] - mn);
      m_i[r] = mn;
      float rs = 0.f;
#pragma unroll
      for (int ni = 0; ni < 4; ++ni) {
        float p = __expf(sacc[ni][r] - mn);
        sacc[ni][r] = p;
        rs += p;
      }
#pragma unroll
      for (int m = 1; m <= 8; m <<= 1) rs += __shfl_xor(rs, m, 64);
      l_i[r] = l_i[r] * al[r] + rs;
    }
#pragma unroll
    for (int r = 0; r < 4; ++r) {
      int q = kg * 4 + r;
#pragma unroll
      for (int ni = 0; ni < 4; ++ni) {
        int sx = ni * 16 + row16;
        int byte = (q * 128 + sx * 2) ^ ((q & 7) << 4);
        *(_Float16*)(pw + byte) = f2h(sacc[ni][r]);
      }
    }
#pragma unroll
    for (int ni = 0; ni < 16; ++ni)
#pragma unroll
      for (int r = 0; r < 4; ++r) yacc[ni][r] *= al[r];
#pragma unroll
    for (int ks2 = 0; ks2 < 2; ++ks2) {
      int pbyte = (row16 * 128 + (ks2 * 32 + koff) * 2) ^ (rswz << 4);
      h8v pa = *(const h8v*)(pw + pbyte);
#pragma unroll
      for (int ni = 0; ni < 16; ++ni) {
        int d = ni * 16 + row16;
        h8v vb = *(const h8v*)(cb + 32768 + d * 128 + ((((ks2 << 2) | kg) ^ rswz) << 4));
        yacc[ni] = MFMA(pa, vb, yacc[ni]);
      }
    }
    if (pf) {
#pragma unroll
      for (int j = 0; j < 4; ++j) {
        int idx = tid + 512 * j;
        *(h8v*)(nb + (idx >> 5) * 512 + (((idx & 31) ^ ((idx >> 5) & 7)) << 4)) = kreg[j];
        *(h8v*)(nb + 32768 + (idx >> 3) * 128 + (((idx & 7) ^ ((idx >> 3) & 7)) << 4)) = vreg[j];
      }
    }
    __syncthreads();
  }

  _Float16* yb = yp + (size_t)(sp * 8 + b) * 2048 * 256;
  float* mm = mlm + (size_t)(sp * 8 + b) * 2048;
  float* ml = mll + (size_t)(sp * 8 + b) * 2048;
#pragma unroll
  for (int r = 0; r < 4; ++r) {
    int q = q0 + kg * 4 + r;
#pragma unroll
    for (int ni = 0; ni < 16; ++ni)
      yb[(size_t)q * 256 + ni * 16 + row16] = f2h(yacc[ni][r]);
    if (row16 == 0) { mm[q] = m_i[r]; ml[q] = l_i[r]; }
  }
}

// ---------------- K6b: combine KV splits
__global__ __launch_bounds__(256) void k_comb(const _Float16* __restrict__ yp,
                                              const float* __restrict__ mlm, const float* __restrict__ mll,
                                              _Float16* __restrict__ yv) {
  int b = blockIdx.y;
  int q = blockIdx.x * 32 + (threadIdx.x >> 3);
  int d0 = (threadIdx.x & 7) * 32;
  float ms[NSPLIT], w[NSPLIT];
  float M = -3e38f;
#pragma unroll
  for (int s = 0; s < NSPLIT; ++s) {
    ms[s] = mlm[(size_t)(s * 8 + b) * 2048 + q];
    M = fmaxf(M, ms[s]);
  }
  float L = 0.f;
#pragma unroll
  for (int s = 0; s < NSPLIT; ++s) {
    w[s] = __expf(ms[s] - M);
    L += w[s] * mll[(size_t)(s * 8 + b) * 2048 + q];
  }
  float inv = 1.f / L;
#pragma unroll
  for (int s = 0; s < NSPLIT; ++s) w[s] *= inv;
  _Float16* out = yv + ((size_t)b * 2048 + q) * 256 + d0;
#pragma unroll
  for (int c = 0; c < 4; ++c) {
    float o[8];
#pragma unroll
    for (int j = 0; j < 8; ++j) o[j] = 0.f;
#pragma unroll
    for (int s = 0; s < NSPLIT; ++s) {
      h8v v = *(const h8v*)(yp + ((size_t)(s * 8 + b) * 2048 + q) * 256 + d0 + c * 8);
#pragma unroll
      for (int j = 0; j < 8; ++j) o[j] += w[s] * (float)v[j];
    }
    h8v ov;
#pragma unroll
    for (int j = 0; j < 8; ++j) ov[j] = f2h(o[j]);
    *(h8v*)(out + c * 8) = ov;
  }
}

// ---------------- K7: out = BN(W@y + Wb) + x2 (LDS-staged GEMM core, f16 residual)
__global__ __launch_bounds__(256, 3) void k_final(const _Float16* __restrict__ Wh,
                                                  const _Float16* __restrict__ yv,
                                                  const float* __restrict__ Wb,
                                                  const float* __restrict__ bng, const float* __restrict__ bnb,
                                                  const float* __restrict__ bnm, const float* __restrict__ bnv,
                                                  const _Float16* __restrict__ x2ct, float* __restrict__ out) {
  int b = blockIdx.z;
  int o0 = blockIdx.y * 128, t0 = blockIdx.x * 128;
  int tid = threadIdx.x;
  int wid = tid >> 6, lane = tid & 63;
  int wm = (wid >> 1) * 64, wn = (wid & 1) * 64;
  int row16 = lane & 15, kg = lane >> 4;
  __shared__ __align__(16) char lA[2][8192];
  __shared__ __align__(16) char lB[2][8192];
  f4v acc[4][4];
#pragma unroll
  for (int mi = 0; mi < 4; ++mi)
#pragma unroll
    for (int ni = 0; ni < 4; ++ni) acc[mi][ni] = (f4v){0.f, 0.f, 0.f, 0.f};
  gemm128_lds(Wh + (size_t)o0 * 256, 256,
              yv + (size_t)b * 2048 * 256 + (size_t)t0 * 256, 256, 256, tid, lA[0], lB[0], acc);
#pragma unroll
  for (int mi = 0; mi < 4; ++mi)
#pragma unroll
    for (int r = 0; r < 4; ++r) {
      int o = o0 + wm + mi * 16 + kg * 4 + r;
      float sc = bng[o] * rsqrtf(bnv[o] + 1e-5f);
      float add = (Wb[o] - bnm[o]) * sc + bnb[o];
#pragma unroll
      for (int ni = 0; ni < 4; ++ni) {
        int t = t0 + wn + ni * 16 + row16;
        size_t idx = ((size_t)b * 512 + o) * 2048 + t;
        out[idx] = acc[mi][ni][r] * sc + add + (float)x2ct[idx];
      }
    }
}

extern "C" void kernel_launch(void* const* d_in, const int* in_sizes, int n_in,
                              void* d_out, int out_size, void* d_ws, size_t ws_size,
                              hipStream_t stream) {
  const float* x    = (const float*)d_in[0];
  const float* tcw1 = (const float*)d_in[1];
  const float* tcw2 = (const float*)d_in[2];
  const float* zw   = (const float*)d_in[3];
  const float* zb   = (const float*)d_in[4];
  const float* gw   = (const float*)d_in[5];
  const float* gb   = (const float*)d_in[6];
  const float* thw  = (const float*)d_in[7];
  const float* thb  = (const float*)d_in[8];
  const float* phw  = (const float*)d_in[9];
  const float* phb  = (const float*)d_in[10];
  const float* Ww   = (const float*)d_in[11];
  const float* Wb   = (const float*)d_in[12];
  const float* bng  = (const float*)d_in[13];
  const float* bnb  = (const float*)d_in[14];
  const float* bnm  = (const float*)d_in[15];
  const float* bnv  = (const float*)d_in[16];

  char* Wp = (char*)d_ws;
  _Float16* xpe = (_Float16*)(Wp);                  // [b][t][c] f16      16,777,216 B
  _Float16* Mh  = (_Float16*)(Wp + 16777216);       // [5][o][c] f16       2,621,440
  _Float16* x2h = (_Float16*)(Wp + 19398656);       // [b][t][c] f16      16,777,216
  _Float16* x2c = (_Float16*)(Wp + 36175872);       // [b][c][t] f16      16,777,216
  _Float16* tht = (_Float16*)(Wp + 69730304);       // [b][t][d] f16       8,388,608
  _Float16* pht = (_Float16*)(Wp + 78118912);       // [b][t][d] f16       8,388,608
  _Float16* gv  = (_Float16*)(Wp + 86507520);       // [b][d][t] f16       8,388,608
  _Float16* yv  = (_Float16*)(Wp + 94896128);       // [b][t][d] f16       8,388,608
  _Float16* wc  = (_Float16*)(Wp + 103284736);      // 4 x 131072 f16      1,048,576
  _Float16* wth = wc, *wph = wc + 131072, *wg = wc + 262144, *wW = wc + 393216;
  _Float16* zh  = (_Float16*)(Wp + 36175872);                // aliases x2c (dead until k_conv)
  _Float16* wt  = (_Float16*)(Wp + 36175872 + 1572864);
  _Float16* yp  = (_Float16*)(Wp);                  // aliases xpe/Mh (dead after k_gtp)
  float*    mlm = (float*)   (Wp + 16777216);
  float*    mll = (float*)   (Wp + 16908288);

  k_cast  <<<dim3(512, 4), 256, 0, stream>>>(thw, phw, gw, Ww, wc);
  k_castz <<<3072, 256, 0, stream>>>(zw, zh);
  k_wtrans<<<dim3(8, 8, 6), 256, 0, stream>>>(tcw1, tcw2, wt);
  k_merge <<<dim3(8, 8, 5), 256, 0, stream>>>(zh, wt, zw, Mh);
  k_pe_t  <<<dim3(64, 16, 8), 256, 0, stream>>>(x, xpe);
  k_conv  <<<dim3(16, 8, 8), 256, 0, stream>>>(Mh, xpe, zb, x2c, x2h);
  k_gtp   <<<dim3(16, 6, 8), 256, 0, stream>>>(x2h, wth, wph, wg, thb, phb, gb, tht, pht, gv);
  k_attn  <<<dim3(16, NSPLIT, 8), 512, 0, stream>>>(tht, pht, gv, yp, mlm, mll);
  k_comb  <<<dim3(64, 8), 256, 0, stream>>>(yp, mlm, mll, yv);
  k_final <<<dim3(16, 4, 8), 256, 0, stream>>>(wW, yv, Wb, bng, bnb, bnm, bnv, x2c, (float*)d_out);
}